// Round 1
// baseline (291.330 us; speedup 1.0000x reference)
//
#include <hip/hip_runtime.h>

#define HWs 25600   // 160*160
#define NB 16       // batches
#define NC 128      // channels
#define NS 256      // selected per batch
#define NN 4096     // NB*NS total rows

// ---------------- K1: copy z -> out (float4 grid-stride) ----------------
__global__ __launch_bounds__(256) void copy_kernel(const float4* __restrict__ in,
                                                   float4* __restrict__ out, int n4) {
  int i = blockIdx.x * blockDim.x + threadIdx.x;
  int stride = gridDim.x * blockDim.x;
  for (; i < n4; i += stride) out[i] = in[i];
}

// ---------------- K2: exact top-256 per batch (ties -> lowest index) ----------------
// Radix-select on raw f32 bits (all scores >= 0 so unsigned compare == float compare).
__global__ __launch_bounds__(256) void topk_kernel(const float* __restrict__ score,
                                                   int* __restrict__ sel) {
  __shared__ unsigned int vals[HWs];          // 100 KB
  __shared__ int hist[256];
  __shared__ int scan_gt[256], scan_eq[256];
  __shared__ int bc_dig, bc_k;

  int b = blockIdx.x;
  int tid = threadIdx.x;
  const float* sc = score + (size_t)b * HWs;
  for (int i = tid; i < HWs; i += 256) vals[i] = __float_as_uint(sc[i]);
  __syncthreads();

  // find value t of the 256th largest via 4 passes of 8-bit digits (MSB first)
  unsigned prefix = 0;
  int k = NS;  // 1-indexed rank among remaining candidates
  for (int d = 3; d >= 0; --d) {
    int sh = d * 8;
    hist[tid] = 0;
    __syncthreads();
    unsigned maskHigh = (d == 3) ? 0u : (0xFFFFFFFFu << (sh + 8));
    for (int i = tid; i < HWs; i += 256) {
      unsigned v = vals[i];
      if ((v & maskHigh) == prefix) atomicAdd(&hist[(v >> sh) & 255], 1);
    }
    __syncthreads();
    if (tid == 0) {
      int cum = 0, dig = 0, kk = k;
      for (int q = 255; q >= 0; --q) {
        if (cum + hist[q] >= kk) { dig = q; bc_k = kk - cum; break; }
        cum += hist[q];
      }
      bc_dig = dig;
    }
    __syncthreads();
    prefix |= ((unsigned)bc_dig) << sh;
    k = bc_k;
    __syncthreads();
  }
  unsigned t = prefix;

  // stable compaction: all v > t, plus first (256 - #gt) elements with v == t by index
  int cstart = tid * 100, cend = cstart + 100;  // 25600 = 256*100
  int cgt = 0, ceq = 0;
  for (int i = cstart; i < cend; ++i) {
    unsigned v = vals[i];
    cgt += (v > t) ? 1 : 0;
    ceq += (v == t) ? 1 : 0;
  }
  scan_gt[tid] = cgt; scan_eq[tid] = ceq;
  __syncthreads();
  for (int off = 1; off < 256; off <<= 1) {   // Hillis-Steele inclusive scan
    int ag = (tid >= off) ? scan_gt[tid - off] : 0;
    int ae = (tid >= off) ? scan_eq[tid - off] : 0;
    __syncthreads();
    scan_gt[tid] += ag; scan_eq[tid] += ae;
    __syncthreads();
  }
  int total_gt = scan_gt[255];
  int need = NS - total_gt;
  int g = scan_gt[tid] - cgt;
  int e = scan_eq[tid] - ceq;
  for (int i = cstart; i < cend; ++i) {
    unsigned v = vals[i];
    if (v > t) { sel[b * NS + g] = i; ++g; }
    else if (v == t) { if (e < need) sel[b * NS + total_gt + e] = i; ++e; }
  }
}

// ---------------- K3: gather selected features + row-normalize ----------------
// one wave per row (row = b*256+s), lane covers channels (lane, lane+64)
__global__ __launch_bounds__(256) void gather_norm_kernel(const float* __restrict__ z,
                                                          const int* __restrict__ sel,
                                                          float* __restrict__ feats,
                                                          float* __restrict__ nf) {
  int row = blockIdx.x * 4 + (threadIdx.x >> 6);
  int lane = threadIdx.x & 63;
  int b = row >> 8;
  int idx = sel[row];
  const float* zb = z + (size_t)b * NC * HWs + idx;
  float v0 = zb[(size_t)lane * HWs];
  float v1 = zb[(size_t)(lane + 64) * HWs];
  float ss = v0 * v0 + v1 * v1;
  #pragma unroll
  for (int off = 32; off; off >>= 1) ss += __shfl_xor(ss, off);
  float norm = sqrtf(ss);
  float denom = fmaxf(norm, 1e-12f);
  feats[row * NC + lane] = v0;
  feats[row * NC + lane + 64] = v1;
  nf[row * NC + lane] = v0 / denom;
  nf[row * NC + lane + 64] = v1 / denom;
}

// ---------------- K4: sim = nf @ nf^T tile, write adjacency bitmask ----------------
// 64x64 tile per block, 256 threads, 4x4 microtile, XOR-swizzled LDS (conflict-free)
__global__ __launch_bounds__(256) void sim_kernel(const float* __restrict__ nf,
                                                  unsigned long long* __restrict__ adj) {
  __shared__ float4 tA[64 * 32];  // 32 KB, swizzled [row][k4]
  __shared__ float4 tB[64 * 32];  // 32 KB
  int I0 = blockIdx.x * 64, J0 = blockIdx.y * 64;
  int tid = threadIdx.x;
  for (int f = tid; f < 64 * 32; f += 256) {
    int r = f >> 5, k4 = f & 31;
    int sw = r * 32 + (k4 ^ ((r >> 2) & 7));
    tA[sw] = *(const float4*)(nf + (size_t)(I0 + r) * NC + k4 * 4);
    tB[sw] = *(const float4*)(nf + (size_t)(J0 + r) * NC + k4 * 4);
  }
  __syncthreads();
  int i0 = (tid & 15) * 4;
  int j0 = (tid >> 4) * 4;
  float acc[4][4] = {};
  for (int k4 = 0; k4 < 32; ++k4) {
    float4 a4[4], b4[4];
    #pragma unroll
    for (int r = 0; r < 4; ++r) a4[r] = tA[(i0 + r) * 32 + (k4 ^ (((i0 + r) >> 2) & 7))];
    #pragma unroll
    for (int s = 0; s < 4; ++s) b4[s] = tB[(j0 + s) * 32 + (k4 ^ (((j0 + s) >> 2) & 7))];
    #pragma unroll
    for (int r = 0; r < 4; ++r)
      #pragma unroll
      for (int s = 0; s < 4; ++s)
        acc[r][s] += a4[r].x * b4[s].x + a4[r].y * b4[s].y + a4[r].z * b4[s].z + a4[r].w * b4[s].w;
  }
  #pragma unroll
  for (int r = 0; r < 4; ++r)
    #pragma unroll
    for (int s = 0; s < 4; ++s) {
      float sim = acc[r][s];
      if ((1.0f - sim) * 0.5f < 0.2f) {   // literal same expression as reference
        int gi = I0 + i0 + r, gj = J0 + j0 + s;
        atomicOr(&adj[gi * 64 + (gj >> 6)], 1ull << (gj & 63));
      }
    }
}

// ---------------- K5a: deg -> dinv via popcount of bitmask rows ----------------
__global__ __launch_bounds__(256) void deg_kernel(const unsigned long long* __restrict__ adj,
                                                  float* __restrict__ dinv) {
  int row = blockIdx.x * 4 + (threadIdx.x >> 6);
  int lane = threadIdx.x & 63;
  int cnt = __popcll(adj[row * 64 + lane]);
  #pragma unroll
  for (int off = 32; off; off >>= 1) cnt += __shfl_xor(cnt, off);
  if (lane == 0) dinv[row] = 1.0f / sqrtf(fmaxf((float)cnt, 1.0f));
}

// ---------------- K5b: agg = dinv .* (A @ (dinv .* feats)) via sparse edge list ----------------
__global__ __launch_bounds__(128) void agg_kernel(const unsigned long long* __restrict__ adj,
                                                  const float* __restrict__ feats,
                                                  const float* __restrict__ dinv,
                                                  float* __restrict__ agg) {
  __shared__ int list[NN];      // worst case all rows adjacent
  __shared__ int cnt_s;
  int row = blockIdx.x;
  int tid = threadIdx.x;
  if (tid < 64) {
    unsigned long long w = adj[row * 64 + tid];
    int c = __popcll(w);
    int x = c;
    #pragma unroll
    for (int off = 1; off < 64; off <<= 1) {
      int y = __shfl_up(x, off);
      if (tid >= off) x += y;
    }
    int pos = x - c;  // exclusive prefix -> deterministic ascending order
    while (w) {
      int bit = __builtin_ctzll(w);
      list[pos++] = tid * 64 + bit;
      w &= w - 1;
    }
    if (tid == 63) cnt_s = x;
  }
  __syncthreads();
  int cnt = cnt_s;
  float di = dinv[row];
  float acc = 0.0f;
  for (int e2 = 0; e2 < cnt; ++e2) {
    int j = list[e2];
    acc += dinv[j] * feats[j * NC + tid];
  }
  agg[row * NC + tid] = di * acc;
}

// ---------------- K6: updated = agg @ W + b, scatter into out ----------------
__global__ __launch_bounds__(256) void out_kernel(const float* __restrict__ agg,
                                                  const float* __restrict__ Wg,
                                                  const float* __restrict__ bias,
                                                  const int* __restrict__ sel,
                                                  float* __restrict__ out) {
  __shared__ __align__(16) float Wt[NC * 132];   // W transposed [cp][c], padded
  __shared__ __align__(16) float aggT[16 * 132];
  int tid = threadIdx.x;
  int r0 = blockIdx.x * 16;
  for (int f = tid; f < NC * NC; f += 256) {
    int c = f >> 7, cp = f & 127;
    Wt[cp * 132 + c] = Wg[f];
  }
  for (int f = tid; f < 16 * NC; f += 256) {
    int r = f >> 7, c = f & 127;
    aggT[r * 132 + c] = agg[(r0 + r) * NC + c];
  }
  __syncthreads();
  int cp = tid & 127;
  int rsub = tid >> 7;
  float acc[8];
  float bb = bias[cp];
  #pragma unroll
  for (int q = 0; q < 8; ++q) acc[q] = bb;
  for (int c4 = 0; c4 < 32; ++c4) {
    float4 w4 = *(const float4*)&Wt[cp * 132 + c4 * 4];
    #pragma unroll
    for (int q = 0; q < 8; ++q) {
      float4 a4 = *(const float4*)&aggT[(rsub + 2 * q) * 132 + c4 * 4];
      acc[q] += a4.x * w4.x + a4.y * w4.y + a4.z * w4.z + a4.w * w4.w;
    }
  }
  #pragma unroll
  for (int q = 0; q < 8; ++q) {
    int row = r0 + rsub + 2 * q;
    int batch = row >> 8;
    int idx = sel[row];
    out[(size_t)(batch * NC + cp) * HWs + idx] = acc[q];
  }
}

extern "C" void kernel_launch(void* const* d_in, const int* in_sizes, int n_in,
                              void* d_out, int out_size, void* d_ws, size_t ws_size,
                              hipStream_t stream) {
  const float* z     = (const float*)d_in[0];
  const float* score = (const float*)d_in[1];
  const float* Wg    = (const float*)d_in[2];
  const float* bg    = (const float*)d_in[3];
  float* out = (float*)d_out;

  char* ws = (char*)d_ws;
  size_t off = 0;
  auto alloc = [&](size_t bytes) {
    void* p = ws + off;
    off = (off + bytes + 255) & ~(size_t)255;
    return p;
  };
  int* sel                 = (int*)alloc(NN * sizeof(int));
  float* feats             = (float*)alloc((size_t)NN * NC * sizeof(float));
  float* nf                = (float*)alloc((size_t)NN * NC * sizeof(float));
  unsigned long long* adj  = (unsigned long long*)alloc((size_t)NN * 64 * sizeof(unsigned long long));
  float* dinv              = (float*)alloc(NN * sizeof(float));
  float* agg               = (float*)alloc((size_t)NN * NC * sizeof(float));

  hipMemsetAsync(adj, 0, (size_t)NN * 64 * sizeof(unsigned long long), stream);
  copy_kernel<<<2048, 256, 0, stream>>>((const float4*)z, (float4*)out, (NB * NC * HWs) / 4);
  topk_kernel<<<NB, 256, 0, stream>>>(score, sel);
  gather_norm_kernel<<<NN / 4, 256, 0, stream>>>(z, sel, feats, nf);
  sim_kernel<<<dim3(64, 64), 256, 0, stream>>>(nf, adj);
  deg_kernel<<<NN / 4, 256, 0, stream>>>(adj, dinv);
  agg_kernel<<<NN, 128, 0, stream>>>(adj, feats, dinv, agg);
  out_kernel<<<NN / 16, 256, 0, stream>>>(agg, Wg, bg, sel, out);
}

// Round 2
// 288.188 us; speedup vs baseline: 1.0109x; 1.0109x over previous
//
#include <hip/hip_runtime.h>

#define HWs 25600   // 160*160
#define NB 16       // batches
#define NC 128      // channels
#define NS 256      // selected per batch
#define NN 4096     // NB*NS total rows

// ---------------- K1: copy z -> out (float4 grid-stride) ----------------
__global__ __launch_bounds__(256) void copy_kernel(const float4* __restrict__ in,
                                                   float4* __restrict__ out, int n4) {
  int i = blockIdx.x * blockDim.x + threadIdx.x;
  int stride = gridDim.x * blockDim.x;
  for (; i < n4; i += stride) out[i] = in[i];
}

// ---------------- K2: exact top-256 per batch (ties -> lowest index) ----------------
// Radix-select on raw f32 bits (all scores >= 0 so unsigned compare == float compare).
__global__ __launch_bounds__(256) void topk_kernel(const float* __restrict__ score,
                                                   int* __restrict__ sel) {
  __shared__ unsigned int vals[HWs];          // 100 KB
  __shared__ int hist[256];
  __shared__ int scan_gt[256], scan_eq[256];
  __shared__ int bc_dig, bc_k;

  int b = blockIdx.x;
  int tid = threadIdx.x;
  const float* sc = score + (size_t)b * HWs;
  for (int i = tid; i < HWs; i += 256) vals[i] = __float_as_uint(sc[i]);
  __syncthreads();

  // find value t of the 256th largest via 4 passes of 8-bit digits (MSB first)
  unsigned prefix = 0;
  int k = NS;  // 1-indexed rank among remaining candidates
  for (int d = 3; d >= 0; --d) {
    int sh = d * 8;
    hist[tid] = 0;
    __syncthreads();
    unsigned maskHigh = (d == 3) ? 0u : (0xFFFFFFFFu << (sh + 8));
    for (int i = tid; i < HWs; i += 256) {
      unsigned v = vals[i];
      if ((v & maskHigh) == prefix) atomicAdd(&hist[(v >> sh) & 255], 1);
    }
    __syncthreads();
    if (tid == 0) {
      int cum = 0, dig = 0, kk = k;
      for (int q = 255; q >= 0; --q) {
        if (cum + hist[q] >= kk) { dig = q; bc_k = kk - cum; break; }
        cum += hist[q];
      }
      bc_dig = dig;
    }
    __syncthreads();
    prefix |= ((unsigned)bc_dig) << sh;
    k = bc_k;
    __syncthreads();
  }
  unsigned t = prefix;

  // stable compaction: all v > t, plus first (256 - #gt) elements with v == t by index
  int cstart = tid * 100, cend = cstart + 100;  // 25600 = 256*100
  int cgt = 0, ceq = 0;
  for (int i = cstart; i < cend; ++i) {
    unsigned v = vals[i];
    cgt += (v > t) ? 1 : 0;
    ceq += (v == t) ? 1 : 0;
  }
  scan_gt[tid] = cgt; scan_eq[tid] = ceq;
  __syncthreads();
  for (int off = 1; off < 256; off <<= 1) {   // Hillis-Steele inclusive scan
    int ag = (tid >= off) ? scan_gt[tid - off] : 0;
    int ae = (tid >= off) ? scan_eq[tid - off] : 0;
    __syncthreads();
    scan_gt[tid] += ag; scan_eq[tid] += ae;
    __syncthreads();
  }
  int total_gt = scan_gt[255];
  int need = NS - total_gt;
  int g = scan_gt[tid] - cgt;
  int e = scan_eq[tid] - ceq;
  for (int i = cstart; i < cend; ++i) {
    unsigned v = vals[i];
    if (v > t) { sel[b * NS + g] = i; ++g; }
    else if (v == t) { if (e < need) sel[b * NS + total_gt + e] = i; ++e; }
  }
}

// ---------------- K3: gather selected features + row-normalize ----------------
// one wave per row (row = b*256+s), lane covers channels (lane, lane+64)
__global__ __launch_bounds__(256) void gather_norm_kernel(const float* __restrict__ z,
                                                          const int* __restrict__ sel,
                                                          float* __restrict__ feats,
                                                          float* __restrict__ nf) {
  int row = blockIdx.x * 4 + (threadIdx.x >> 6);
  int lane = threadIdx.x & 63;
  int b = row >> 8;
  int idx = sel[row];
  const float* zb = z + (size_t)b * NC * HWs + idx;
  float v0 = zb[(size_t)lane * HWs];
  float v1 = zb[(size_t)(lane + 64) * HWs];
  float ss = v0 * v0 + v1 * v1;
  #pragma unroll
  for (int off = 32; off; off >>= 1) ss += __shfl_xor(ss, off);
  float norm = sqrtf(ss);
  float denom = fmaxf(norm, 1e-12f);
  feats[row * NC + lane] = v0;
  feats[row * NC + lane + 64] = v1;
  nf[row * NC + lane] = v0 / denom;
  nf[row * NC + lane + 64] = v1 / denom;
}

// ---------------- K4: sim = nf @ nf^T tile -> adjacency words, NO global atomics ----------------
// Block (bx,by): rows I0..I0+63 vs cols J0..J0+63 == adj word `by` of each row.
// Bits accumulate in LDS rowbits[64]; each (row, word) written by exactly one block,
// so adj needs NO zero-fill (kills the 119us rocclr fillBuffer).
__global__ __launch_bounds__(256) void sim_kernel(const float* __restrict__ nf,
                                                  unsigned long long* __restrict__ adj) {
  __shared__ float4 tA[64 * 32];  // 32 KB, swizzled [row][k4]
  __shared__ float4 tB[64 * 32];  // 32 KB
  __shared__ unsigned long long rowbits[64];
  int I0 = blockIdx.x * 64, J0 = blockIdx.y * 64;
  int tid = threadIdx.x;
  if (tid < 64) rowbits[tid] = 0ull;
  for (int f = tid; f < 64 * 32; f += 256) {
    int r = f >> 5, k4 = f & 31;
    int sw = r * 32 + (k4 ^ ((r >> 2) & 7));
    tA[sw] = *(const float4*)(nf + (size_t)(I0 + r) * NC + k4 * 4);
    tB[sw] = *(const float4*)(nf + (size_t)(J0 + r) * NC + k4 * 4);
  }
  __syncthreads();
  int i0 = (tid & 15) * 4;
  int j0 = (tid >> 4) * 4;
  float acc[4][4] = {};
  for (int k4 = 0; k4 < 32; ++k4) {
    float4 a4[4], b4[4];
    #pragma unroll
    for (int r = 0; r < 4; ++r) a4[r] = tA[(i0 + r) * 32 + (k4 ^ (((i0 + r) >> 2) & 7))];
    #pragma unroll
    for (int s = 0; s < 4; ++s) b4[s] = tB[(j0 + s) * 32 + (k4 ^ (((j0 + s) >> 2) & 7))];
    #pragma unroll
    for (int r = 0; r < 4; ++r)
      #pragma unroll
      for (int s = 0; s < 4; ++s)
        acc[r][s] += a4[r].x * b4[s].x + a4[r].y * b4[s].y + a4[r].z * b4[s].z + a4[r].w * b4[s].w;
  }
  #pragma unroll
  for (int r = 0; r < 4; ++r) {
    unsigned long long m = 0ull;
    #pragma unroll
    for (int s = 0; s < 4; ++s) {
      float sim = acc[r][s];
      if ((1.0f - sim) * 0.5f < 0.2f)       // literal same expression as reference
        m |= 1ull << (j0 + s);
    }
    if (m) atomicOr(&rowbits[i0 + r], m);   // LDS atomic, fires only on true edges
  }
  __syncthreads();
  if (tid < 64) adj[(size_t)(I0 + tid) * 64 + blockIdx.y] = rowbits[tid];
}

// ---------------- K5a: deg -> dinv via popcount of bitmask rows ----------------
__global__ __launch_bounds__(256) void deg_kernel(const unsigned long long* __restrict__ adj,
                                                  float* __restrict__ dinv) {
  int row = blockIdx.x * 4 + (threadIdx.x >> 6);
  int lane = threadIdx.x & 63;
  int cnt = __popcll(adj[row * 64 + lane]);
  #pragma unroll
  for (int off = 32; off; off >>= 1) cnt += __shfl_xor(cnt, off);
  if (lane == 0) dinv[row] = 1.0f / sqrtf(fmaxf((float)cnt, 1.0f));
}

// ---------------- K5b: agg = dinv .* (A @ (dinv .* feats)) via sparse edge list ----------------
__global__ __launch_bounds__(128) void agg_kernel(const unsigned long long* __restrict__ adj,
                                                  const float* __restrict__ feats,
                                                  const float* __restrict__ dinv,
                                                  float* __restrict__ agg) {
  __shared__ int list[NN];      // worst case all rows adjacent
  __shared__ int cnt_s;
  int row = blockIdx.x;
  int tid = threadIdx.x;
  if (tid < 64) {
    unsigned long long w = adj[row * 64 + tid];
    int c = __popcll(w);
    int x = c;
    #pragma unroll
    for (int off = 1; off < 64; off <<= 1) {
      int y = __shfl_up(x, off);
      if (tid >= off) x += y;
    }
    int pos = x - c;  // exclusive prefix -> deterministic ascending order
    while (w) {
      int bit = __builtin_ctzll(w);
      list[pos++] = tid * 64 + bit;
      w &= w - 1;
    }
    if (tid == 63) cnt_s = x;
  }
  __syncthreads();
  int cnt = cnt_s;
  float di = dinv[row];
  float acc = 0.0f;
  for (int e2 = 0; e2 < cnt; ++e2) {
    int j = list[e2];
    acc += dinv[j] * feats[j * NC + tid];
  }
  agg[row * NC + tid] = di * acc;
}

// ---------------- K6: updated = agg @ W + b, scatter into out ----------------
__global__ __launch_bounds__(256) void out_kernel(const float* __restrict__ agg,
                                                  const float* __restrict__ Wg,
                                                  const float* __restrict__ bias,
                                                  const int* __restrict__ sel,
                                                  float* __restrict__ out) {
  __shared__ __align__(16) float Wt[NC * 132];   // W transposed [cp][c], padded
  __shared__ __align__(16) float aggT[16 * 132];
  int tid = threadIdx.x;
  int r0 = blockIdx.x * 16;
  for (int f = tid; f < NC * NC; f += 256) {
    int c = f >> 7, cp = f & 127;
    Wt[cp * 132 + c] = Wg[f];
  }
  for (int f = tid; f < 16 * NC; f += 256) {
    int r = f >> 7, c = f & 127;
    aggT[r * 132 + c] = agg[(r0 + r) * NC + c];
  }
  __syncthreads();
  int cp = tid & 127;
  int rsub = tid >> 7;
  float acc[8];
  float bb = bias[cp];
  #pragma unroll
  for (int q = 0; q < 8; ++q) acc[q] = bb;
  for (int c4 = 0; c4 < 32; ++c4) {
    float4 w4 = *(const float4*)&Wt[cp * 132 + c4 * 4];
    #pragma unroll
    for (int q = 0; q < 8; ++q) {
      float4 a4 = *(const float4*)&aggT[(rsub + 2 * q) * 132 + c4 * 4];
      acc[q] += a4.x * w4.x + a4.y * w4.y + a4.z * w4.z + a4.w * w4.w;
    }
  }
  #pragma unroll
  for (int q = 0; q < 8; ++q) {
    int row = r0 + rsub + 2 * q;
    int batch = row >> 8;
    int idx = sel[row];
    out[(size_t)(batch * NC + cp) * HWs + idx] = acc[q];
  }
}

extern "C" void kernel_launch(void* const* d_in, const int* in_sizes, int n_in,
                              void* d_out, int out_size, void* d_ws, size_t ws_size,
                              hipStream_t stream) {
  const float* z     = (const float*)d_in[0];
  const float* score = (const float*)d_in[1];
  const float* Wg    = (const float*)d_in[2];
  const float* bg    = (const float*)d_in[3];
  float* out = (float*)d_out;

  char* ws = (char*)d_ws;
  size_t off = 0;
  auto alloc = [&](size_t bytes) {
    void* p = ws + off;
    off = (off + bytes + 255) & ~(size_t)255;
    return p;
  };
  int* sel                 = (int*)alloc(NN * sizeof(int));
  float* feats             = (float*)alloc((size_t)NN * NC * sizeof(float));
  float* nf                = (float*)alloc((size_t)NN * NC * sizeof(float));
  unsigned long long* adj  = (unsigned long long*)alloc((size_t)NN * 64 * sizeof(unsigned long long));
  float* dinv              = (float*)alloc(NN * sizeof(float));
  float* agg               = (float*)alloc((size_t)NN * NC * sizeof(float));

  copy_kernel<<<2048, 256, 0, stream>>>((const float4*)z, (float4*)out, (NB * NC * HWs) / 4);
  topk_kernel<<<NB, 256, 0, stream>>>(score, sel);
  gather_norm_kernel<<<NN / 4, 256, 0, stream>>>(z, sel, feats, nf);
  sim_kernel<<<dim3(64, 64), 256, 0, stream>>>(nf, adj);
  deg_kernel<<<NN / 4, 256, 0, stream>>>(adj, dinv);
  agg_kernel<<<NN, 128, 0, stream>>>(adj, feats, dinv, agg);
  out_kernel<<<NN / 16, 256, 0, stream>>>(agg, Wg, bg, sel, out);
}

// Round 3
// 189.012 us; speedup vs baseline: 1.5413x; 1.5247x over previous
//
#include <hip/hip_runtime.h>
#include <hip/hip_bf16.h>

#define HWs 25600   // 160*160
#define NB 16       // batches
#define NC 128      // channels
#define NS 256      // selected per batch
#define NN 4096     // NB*NS total rows

typedef __attribute__((ext_vector_type(8))) short bf16x8;   // 8 bf16 = 4 VGPRs
typedef __attribute__((ext_vector_type(4))) float f32x4;
typedef __attribute__((ext_vector_type(4))) int i32x4;

// ---------------- K1: copy z -> out (float4 grid-stride) ----------------
__global__ __launch_bounds__(256) void copy_kernel(const float4* __restrict__ in,
                                                   float4* __restrict__ out, int n4) {
  int i = blockIdx.x * blockDim.x + threadIdx.x;
  int stride = gridDim.x * blockDim.x;
  for (; i < n4; i += stride) out[i] = in[i];
}

// ---------------- K2: exact top-256 per batch (ties -> lowest index) ----------------
// Radix-select on raw f32 bits (scores >= 0 so unsigned compare == float compare).
// Digit selection now fully parallel (suffix-scan), no serial tid-0 loop.
__global__ __launch_bounds__(256) void topk_kernel(const float* __restrict__ score,
                                                   int* __restrict__ sel) {
  __shared__ unsigned int vals[HWs];          // 100 KB
  __shared__ int hist[256];
  __shared__ int scan_s[256];
  __shared__ int scan_eq[256];
  __shared__ int bc_dig, bc_k;

  int b = blockIdx.x;
  int tid = threadIdx.x;
  const float* sc = score + (size_t)b * HWs;
  for (int i = tid; i < HWs; i += 256) vals[i] = __float_as_uint(sc[i]);
  __syncthreads();

  unsigned prefix = 0;
  int k = NS;  // 1-indexed rank among remaining candidates
  for (int d = 3; d >= 0; --d) {
    int sh = d * 8;
    hist[tid] = 0;
    __syncthreads();
    unsigned maskHigh = (d == 3) ? 0u : (0xFFFFFFFFu << (sh + 8));
    for (int i = tid; i < HWs; i += 256) {
      unsigned v = vals[i];
      if ((v & maskHigh) == prefix) atomicAdd(&hist[(v >> sh) & 255], 1);
    }
    __syncthreads();
    // suffix-sum: scan_s[t] = sum of hist[255-t .. 255]  (inclusive scan of reversed)
    int v = hist[255 - tid];
    scan_s[tid] = v;
    __syncthreads();
    for (int off = 1; off < 256; off <<= 1) {
      int a = (tid >= off) ? scan_s[tid - off] : 0;
      __syncthreads();
      scan_s[tid] += a;
      __syncthreads();
    }
    int q = 255 - tid;
    int Sq = scan_s[tid];          // count of elements with digit >= q
    int before = Sq - hist[q];     // count with digit > q
    if (before < k && k <= Sq) { bc_dig = q; bc_k = k - before; }  // exactly one thread
    __syncthreads();
    prefix |= ((unsigned)bc_dig) << sh;
    k = bc_k;
    __syncthreads();
  }
  unsigned t = prefix;

  // stable compaction: all v > t, plus first (256 - #gt) elements with v == t by index
  int cstart = tid * 100, cend = cstart + 100;  // 25600 = 256*100
  int cgt = 0, ceq = 0;
  for (int i = cstart; i < cend; ++i) {
    unsigned v = vals[i];
    cgt += (v > t) ? 1 : 0;
    ceq += (v == t) ? 1 : 0;
  }
  scan_s[tid] = cgt; scan_eq[tid] = ceq;
  __syncthreads();
  for (int off = 1; off < 256; off <<= 1) {   // Hillis-Steele inclusive scan
    int ag = (tid >= off) ? scan_s[tid - off] : 0;
    int ae = (tid >= off) ? scan_eq[tid - off] : 0;
    __syncthreads();
    scan_s[tid] += ag; scan_eq[tid] += ae;
    __syncthreads();
  }
  int total_gt = scan_s[255];
  int need = NS - total_gt;
  int g = scan_s[tid] - cgt;
  int e = scan_eq[tid] - ceq;
  for (int i = cstart; i < cend; ++i) {
    unsigned v = vals[i];
    if (v > t) { sel[b * NS + g] = i; ++g; }
    else if (v == t) { if (e < need) sel[b * NS + total_gt + e] = i; ++e; }
  }
}

// ---------------- K3: gather selected features + row-normalize (f32 feats + bf16 nf) ----------------
__global__ __launch_bounds__(256) void gather_norm_kernel(const float* __restrict__ z,
                                                          const int* __restrict__ sel,
                                                          float* __restrict__ feats,
                                                          __hip_bfloat16* __restrict__ nfb) {
  int row = blockIdx.x * 4 + (threadIdx.x >> 6);
  int lane = threadIdx.x & 63;
  int b = row >> 8;
  int idx = sel[row];
  const float* zb = z + (size_t)b * NC * HWs + idx;
  float v0 = zb[(size_t)lane * HWs];
  float v1 = zb[(size_t)(lane + 64) * HWs];
  float ss = v0 * v0 + v1 * v1;
  #pragma unroll
  for (int off = 32; off; off >>= 1) ss += __shfl_xor(ss, off);
  float norm = sqrtf(ss);
  float denom = fmaxf(norm, 1e-12f);
  feats[row * NC + lane] = v0;
  feats[row * NC + lane + 64] = v1;
  nfb[row * NC + lane] = __float2bfloat16(v0 / denom);
  nfb[row * NC + lane + 64] = __float2bfloat16(v1 / denom);
}

// ---------------- K4: sim = nf @ nf^T via bf16 MFMA -> adjacency words ----------------
// Block (bx,by): rows I0..I0+63 x cols J0..J0+63 == adj word `by` of each row.
// 4 waves; wave w computes rows 16w..16w+15 x all 64 cols (4 acc tiles).
// LDS tiles XOR-swizzled (chunk ^= row&7) -> conflict-free ds_read_b128 frags.
__global__ __launch_bounds__(256) void sim_kernel(const ushort* __restrict__ nfb,
                                                  unsigned long long* __restrict__ adj) {
  __shared__ __align__(16) ushort tA[64 * 128];   // 16 KB
  __shared__ __align__(16) ushort tB[64 * 128];   // 16 KB
  __shared__ unsigned long long rowbits[64];
  int I0 = blockIdx.x * 64, J0 = blockIdx.y * 64;
  int tid = threadIdx.x;
  if (tid < 64) rowbits[tid] = 0ull;
  // stage: 1024 16B chunks per tile (row r, chunk c -> swizzled chunk c^(r&7))
  for (int f = tid; f < 1024; f += 256) {
    int r = f >> 4, c = f & 15;
    int scnk = c ^ (r & 7);
    *(i32x4*)&tA[r * 128 + scnk * 8] = *(const i32x4*)(nfb + (size_t)(I0 + r) * NC + c * 8);
    *(i32x4*)&tB[r * 128 + scnk * 8] = *(const i32x4*)(nfb + (size_t)(J0 + r) * NC + c * 8);
  }
  __syncthreads();
  int w = tid >> 6, l = tid & 63;
  int r = l & 15, kg = l >> 4;
  f32x4 acc[4] = {{0.f, 0.f, 0.f, 0.f}, {0.f, 0.f, 0.f, 0.f},
                  {0.f, 0.f, 0.f, 0.f}, {0.f, 0.f, 0.f, 0.f}};
  int Ar = 16 * w + r;
  #pragma unroll
  for (int kk = 0; kk < 4; ++kk) {            // k0 = 32*kk; lane k = 32*kk + 8*kg + j
    int chunkA = (kk * 4 + kg) ^ (Ar & 7);
    bf16x8 a = *(bf16x8*)&tA[Ar * 128 + chunkA * 8];
    #pragma unroll
    for (int j = 0; j < 4; ++j) {
      int Bc = 16 * j + r;
      int chunkB = (kk * 4 + kg) ^ (Bc & 7);
      bf16x8 bf = *(bf16x8*)&tB[Bc * 128 + chunkB * 8];
      acc[j] = __builtin_amdgcn_mfma_f32_16x16x32_bf16(a, bf, acc[j], 0, 0, 0);
    }
  }
  // D layout: col = lane&15 (within 16-col tile j), row = 16w + (lane>>4)*4 + q
  #pragma unroll
  for (int q = 0; q < 4; ++q) {
    unsigned long long m = 0ull;
    #pragma unroll
    for (int j = 0; j < 4; ++j) {
      float sim = acc[j][q];
      if ((1.0f - sim) * 0.5f < 0.2f)          // literal same expression as reference
        m |= 1ull << (16 * j + (l & 15));
    }
    if (m) atomicOr(&rowbits[16 * w + (l >> 4) * 4 + q], m);  // LDS atomic, rare
  }
  __syncthreads();
  if (tid < 64) adj[(size_t)(I0 + tid) * 64 + blockIdx.y] = rowbits[tid];
}

// ---------------- K5a: deg -> dinv via popcount of bitmask rows ----------------
__global__ __launch_bounds__(256) void deg_kernel(const unsigned long long* __restrict__ adj,
                                                  float* __restrict__ dinv) {
  int row = blockIdx.x * 4 + (threadIdx.x >> 6);
  int lane = threadIdx.x & 63;
  int cnt = __popcll(adj[row * 64 + lane]);
  #pragma unroll
  for (int off = 32; off; off >>= 1) cnt += __shfl_xor(cnt, off);
  if (lane == 0) dinv[row] = 1.0f / sqrtf(fmaxf((float)cnt, 1.0f));
}

// ---------------- K5b: agg = dinv .* (A @ (dinv .* feats)) via sparse edge list ----------------
__global__ __launch_bounds__(128) void agg_kernel(const unsigned long long* __restrict__ adj,
                                                  const float* __restrict__ feats,
                                                  const float* __restrict__ dinv,
                                                  float* __restrict__ agg) {
  __shared__ int list[NN];
  __shared__ int cnt_s;
  int row = blockIdx.x;
  int tid = threadIdx.x;
  if (tid < 64) {
    unsigned long long w = adj[row * 64 + tid];
    int c = __popcll(w);
    int x = c;
    #pragma unroll
    for (int off = 1; off < 64; off <<= 1) {
      int y = __shfl_up(x, off);
      if (tid >= off) x += y;
    }
    int pos = x - c;  // exclusive prefix -> deterministic ascending order
    while (w) {
      int bit = __builtin_ctzll(w);
      list[pos++] = tid * 64 + bit;
      w &= w - 1;
    }
    if (tid == 63) cnt_s = x;
  }
  __syncthreads();
  int cnt = cnt_s;
  float di = dinv[row];
  float acc = 0.0f;
  for (int e2 = 0; e2 < cnt; ++e2) {
    int j = list[e2];
    acc += dinv[j] * feats[j * NC + tid];
  }
  agg[row * NC + tid] = di * acc;
}

// ---------------- K6: updated = agg @ W + b, scatter into out ----------------
__global__ __launch_bounds__(256) void out_kernel(const float* __restrict__ agg,
                                                  const float* __restrict__ Wg,
                                                  const float* __restrict__ bias,
                                                  const int* __restrict__ sel,
                                                  float* __restrict__ out) {
  __shared__ __align__(16) float Wt[NC * 132];   // W transposed [cp][c], padded
  __shared__ __align__(16) float aggT[16 * 132];
  int tid = threadIdx.x;
  int r0 = blockIdx.x * 16;
  for (int f = tid; f < NC * NC; f += 256) {
    int c = f >> 7, cp = f & 127;
    Wt[cp * 132 + c] = Wg[f];
  }
  for (int f = tid; f < 16 * NC; f += 256) {
    int r = f >> 7, c = f & 127;
    aggT[r * 132 + c] = agg[(r0 + r) * NC + c];
  }
  __syncthreads();
  int cp = tid & 127;
  int rsub = tid >> 7;
  float acc[8];
  float bb = bias[cp];
  #pragma unroll
  for (int q = 0; q < 8; ++q) acc[q] = bb;
  for (int c4 = 0; c4 < 32; ++c4) {
    float4 w4 = *(const float4*)&Wt[cp * 132 + c4 * 4];
    #pragma unroll
    for (int q = 0; q < 8; ++q) {
      float4 a4 = *(const float4*)&aggT[(rsub + 2 * q) * 132 + c4 * 4];
      acc[q] += a4.x * w4.x + a4.y * w4.y + a4.z * w4.z + a4.w * w4.w;
    }
  }
  #pragma unroll
  for (int q = 0; q < 8; ++q) {
    int row = r0 + rsub + 2 * q;
    int batch = row >> 8;
    int idx = sel[row];
    out[(size_t)(batch * NC + cp) * HWs + idx] = acc[q];
  }
}

extern "C" void kernel_launch(void* const* d_in, const int* in_sizes, int n_in,
                              void* d_out, int out_size, void* d_ws, size_t ws_size,
                              hipStream_t stream) {
  const float* z     = (const float*)d_in[0];
  const float* score = (const float*)d_in[1];
  const float* Wg    = (const float*)d_in[2];
  const float* bg    = (const float*)d_in[3];
  float* out = (float*)d_out;

  char* ws = (char*)d_ws;
  size_t off = 0;
  auto alloc = [&](size_t bytes) {
    void* p = ws + off;
    off = (off + bytes + 255) & ~(size_t)255;
    return p;
  };
  int* sel                 = (int*)alloc(NN * sizeof(int));
  float* feats             = (float*)alloc((size_t)NN * NC * sizeof(float));
  __hip_bfloat16* nfb      = (__hip_bfloat16*)alloc((size_t)NN * NC * sizeof(__hip_bfloat16));
  unsigned long long* adj  = (unsigned long long*)alloc((size_t)NN * 64 * sizeof(unsigned long long));
  float* dinv              = (float*)alloc(NN * sizeof(float));
  float* agg               = (float*)alloc((size_t)NN * NC * sizeof(float));

  copy_kernel<<<2048, 256, 0, stream>>>((const float4*)z, (float4*)out, (NB * NC * HWs) / 4);
  topk_kernel<<<NB, 256, 0, stream>>>(score, sel);
  gather_norm_kernel<<<NN / 4, 256, 0, stream>>>(z, sel, feats, nfb);
  sim_kernel<<<dim3(64, 64), 256, 0, stream>>>((const ushort*)nfb, adj);
  deg_kernel<<<NN / 4, 256, 0, stream>>>(adj, dinv);
  agg_kernel<<<NN, 128, 0, stream>>>(adj, feats, dinv, agg);
  out_kernel<<<NN / 16, 256, 0, stream>>>(agg, Wg, bg, sel, out);
}